// Round 1
// baseline (1207.498 us; speedup 1.0000x reference)
//
#include <hip/hip_runtime.h>

typedef __attribute__((ext_vector_type(4))) float f32x4;
typedef __attribute__((ext_vector_type(8))) __bf16 bf16x8;

__device__ __forceinline__ unsigned short f2bf(float f) {
  union { float f; unsigned u; } v; v.f = f;
  unsigned r = v.u + 0x7fffu + ((v.u >> 16) & 1u);
  return (unsigned short)(r >> 16);
}

__device__ __forceinline__ void gll16(const void* g, void* s) {
  __builtin_amdgcn_global_load_lds((const __attribute__((address_space(1))) unsigned int*)g,
                                   (__attribute__((address_space(3))) unsigned int*)s, 16, 0, 0);
}

#define MFMA(a, b, c) __builtin_amdgcn_mfma_f32_16x16x32_bf16((a), (b), (c), 0, 0, 0)

// ---------------- fp32 -> bf16 convert (x, w_qkv, w_out) ----------------
__global__ __launch_bounds__(256) void convert_kernel(
    const float* __restrict__ x, const float* __restrict__ wqkv, const float* __restrict__ wout,
    unsigned short* __restrict__ xb, unsigned short* __restrict__ wqkvb,
    unsigned short* __restrict__ woutb) {
  const long i4 = (long)blockIdx.x * 256 + threadIdx.x;
  const float4* src;
  unsigned short* dst;
  long j;
  if (i4 < 2097152) { src = (const float4*)x; j = i4; dst = xb; }
  else if (i4 < 2883584) { src = (const float4*)wqkv; j = i4 - 2097152; dst = wqkvb; }
  else { src = (const float4*)wout; j = i4 - 2883584; dst = woutb; }
  const float4 v = src[j];
  ushort4 r;
  r.x = f2bf(v.x); r.y = f2bf(v.y); r.z = f2bf(v.z); r.w = f2bf(v.w);
  *(ushort4*)(dst + j * 4) = r;
}

// ---------------- shared 128x128 GEMM mainloop (A, B row-major [*,1024], NT) ----------------
// LDS layout: row-major [128][64] bf16, 16B blocks XOR-swizzled: block x stored at x^(row&7).
__device__ __forceinline__ void gemm_tile(const unsigned short* __restrict__ A,
                                          const unsigned short* __restrict__ B,
                                          unsigned short* As, unsigned short* Bs,
                                          int tm, int tn, f32x4 acc[4][4]) {
  const int tid = threadIdx.x;
  const int w = tid >> 6, l = tid & 63, lane15 = l & 15, quad = l >> 4;
#pragma unroll
  for (int br = 0; br < 4; ++br)
#pragma unroll
    for (int bc = 0; bc < 4; ++bc) acc[br][bc] = f32x4{0.f, 0.f, 0.f, 0.f};
  const int ar0 = 64 * (w >> 1), bc0 = 64 * (w & 1);
  for (int st = 0; st < 16; ++st) {
    const int kc = st * 64;
#pragma unroll
    for (int t = 0; t < 4; ++t) {
      const int ck = w * 4 + t;          // 1KB chunk id 0..15
      const int row = ck * 8 + (l >> 3); // 8 rows per chunk
      const int x = (l & 7) ^ (row & 7); // swizzled source block
      gll16(A + (size_t)(tm * 128 + row) * 1024 + kc + x * 8, As + ck * 512);
      gll16(B + (size_t)(tn * 128 + row) * 1024 + kc + x * 8, Bs + ck * 512);
    }
    __syncthreads();
#pragma unroll
    for (int kk = 0; kk < 2; ++kk) {
      bf16x8 a[4], b[4];
#pragma unroll
      for (int br = 0; br < 4; ++br) {
        const int row = ar0 + 16 * br + lane15;
        const int x = kk * 4 + quad;
        a[br] = *(const bf16x8*)(As + row * 64 + ((x ^ (row & 7)) * 8));
      }
#pragma unroll
      for (int bc = 0; bc < 4; ++bc) {
        const int row = bc0 + 16 * bc + lane15;
        const int x = kk * 4 + quad;
        b[bc] = *(const bf16x8*)(Bs + row * 64 + ((x ^ (row & 7)) * 8));
      }
#pragma unroll
      for (int br = 0; br < 4; ++br)
#pragma unroll
        for (int bc = 0; bc < 4; ++bc)
          acc[br][bc] = MFMA(a[br], b[bc], acc[br][bc]);
    }
    __syncthreads();
  }
}

// ---------------- QKV projection: qkv = x @ w_qkv^T + b; Q prescaled 1/32; V transposed ----------------
__global__ __launch_bounds__(256) void qkv_kernel(
    const unsigned short* __restrict__ xb, const unsigned short* __restrict__ wb,
    const float* __restrict__ bias, unsigned short* __restrict__ Qp,
    unsigned short* __restrict__ Kp, unsigned short* __restrict__ Vtp) {
  __shared__ unsigned short As[128 * 64], Bs[128 * 64];
  const int bx = blockIdx.x;
  const int tn = bx % 24, tm = bx / 24;
  f32x4 acc[4][4];
  gemm_tile(xb, wb, As, Bs, tm, tn, acc);
  const int tid = threadIdx.x, w = tid >> 6, l = tid & 63, lane15 = l & 15, quad = l >> 4;
  const int r0 = tm * 128 + 64 * (w >> 1);
  const int c0 = tn * 128 + 64 * (w & 1);
  float bq[4];
#pragma unroll
  for (int bc = 0; bc < 4; ++bc) bq[bc] = bias[c0 + 16 * bc + lane15];
  if (tn < 8) {  // Q region, fold 1/sqrt(D)
#pragma unroll
    for (int br = 0; br < 4; ++br)
#pragma unroll
      for (int bc = 0; bc < 4; ++bc)
#pragma unroll
        for (int i = 0; i < 4; ++i)
          Qp[(size_t)(r0 + 16 * br + 4 * quad + i) * 1024 + c0 + 16 * bc + lane15] =
              f2bf((acc[br][bc][i] + bq[bc]) * 0.03125f);
  } else if (tn < 16) {  // K region
#pragma unroll
    for (int br = 0; br < 4; ++br)
#pragma unroll
      for (int bc = 0; bc < 4; ++bc)
#pragma unroll
        for (int i = 0; i < 4; ++i)
          Kp[(size_t)(r0 + 16 * br + 4 * quad + i) * 1024 + c0 - 1024 + 16 * bc + lane15] =
              f2bf(acc[br][bc][i] + bq[bc]);
  } else {  // V region -> transposed store Vt[d][s]
#pragma unroll
    for (int br = 0; br < 4; ++br)
#pragma unroll
      for (int bc = 0; bc < 4; ++bc) {
        ushort4 pk;
        pk.x = f2bf(acc[br][bc][0] + bq[bc]);
        pk.y = f2bf(acc[br][bc][1] + bq[bc]);
        pk.z = f2bf(acc[br][bc][2] + bq[bc]);
        pk.w = f2bf(acc[br][bc][3] + bq[bc]);
        *(ushort4*)(Vtp + (size_t)(c0 - 2048 + 16 * bc + lane15) * 8192 + r0 + 16 * br + 4 * quad) = pk;
      }
  }
}

// ---------------- flash attention: BM=64 rows/wg, BN=256 cols/iter, 8 waves, split-K ----------------
__global__ __launch_bounds__(512, 2) void flash_kernel(
    const unsigned short* __restrict__ Qg, const unsigned short* __restrict__ Kg,
    const unsigned short* __restrict__ Vtg, float* __restrict__ Opart,
    float* __restrict__ mlb, unsigned short* __restrict__ ctx, int nsplit) {
  __shared__ unsigned short Qs[2][64 * 128];  // double-buffered Q k-chunk, swizzled
  __shared__ unsigned short Ps[64 * 128];     // P half (128 cols), swizzled
  __shared__ float sm_wred[8][64];
  __shared__ float sm_wsum[8][64];
  __shared__ float sm_m[64], sm_l[64], sm_alpha[64];

  const int tid = threadIdx.x;
  const int w = tid >> 6, l = tid & 63, lane15 = l & 15, quad = l >> 4;
  const int bx = blockIdx.x;
  const int qt = (nsplit == 2) ? (bx >> 1) : bx;
  const int sp = (nsplit == 2) ? (bx & 1) : 0;
  const int jper = (nsplit == 2) ? 16 : 32;
  const int jstart = sp * jper;
  const int qrow0 = qt * 64;

  f32x4 acc_o[4][8];
#pragma unroll
  for (int br = 0; br < 4; ++br)
#pragma unroll
    for (int bc = 0; bc < 8; ++bc) acc_o[br][bc] = f32x4{0.f, 0.f, 0.f, 0.f};
  f32x4 acc_s[4][2];

  if (tid < 64) { sm_m[tid] = -1e30f; sm_l[tid] = 0.f; }

  auto stageQ = [&](int buf, int c) {
#pragma unroll
    for (int t = 0; t < 2; ++t) {
      const int ck = w * 2 + t;       // 1KB chunk 0..15 (4 rows each)
      const int row = ck * 4 + quad;  // this lane's row
      const int x = lane15 ^ (row & 15);
      gll16(Qg + (size_t)(qrow0 + row) * 1024 + c * 128 + x * 8, &Qs[buf][ck * 512]);
    }
  };

  stageQ(0, 0);
  __syncthreads();

  for (int j = jstart; j < jstart + jper; ++j) {
    const int jb = j * 256;
#pragma unroll
    for (int br = 0; br < 4; ++br) {
      acc_s[br][0] = f32x4{0.f, 0.f, 0.f, 0.f};
      acc_s[br][1] = f32x4{0.f, 0.f, 0.f, 0.f};
    }
    // ---- phase A: S = Q @ K^T (Q prescaled), wave w owns S cols [32w, 32w+32) ----
#pragma unroll 1
    for (int c = 0; c < 8; ++c) {
      stageQ((c + 1) & 1, (c < 7) ? (c + 1) : 0);
      const int buf = c & 1;
      const unsigned short* kb =
          Kg + (size_t)(jb + 32 * w + lane15) * 1024 + c * 128 + quad * 8;
#pragma unroll
      for (int kst = 0; kst < 4; ++kst) {
        bf16x8 a[4];
#pragma unroll
        for (int br = 0; br < 4; ++br) {
          const int row = 16 * br + lane15;
          const int x = kst * 4 + quad;
          a[br] = *(const bf16x8*)(&Qs[buf][row * 128 + ((x ^ (row & 15)) * 8)]);
        }
        const bf16x8 b0 = *(const bf16x8*)(kb + kst * 32);
        const bf16x8 b1 = *(const bf16x8*)(kb + 16 * 1024 + kst * 32);
#pragma unroll
        for (int br = 0; br < 4; ++br) {
          acc_s[br][0] = MFMA(a[br], b0, acc_s[br][0]);
          acc_s[br][1] = MFMA(a[br], b1, acc_s[br][1]);
        }
      }
      __syncthreads();
    }
    // ---- phase B: online softmax ----
#pragma unroll
    for (int br = 0; br < 4; ++br)
#pragma unroll
      for (int i = 0; i < 4; ++i) {
        float t = fmaxf(acc_s[br][0][i], acc_s[br][1][i]);
        t = fmaxf(t, __shfl_xor(t, 1));
        t = fmaxf(t, __shfl_xor(t, 2));
        t = fmaxf(t, __shfl_xor(t, 4));
        t = fmaxf(t, __shfl_xor(t, 8));
        if (lane15 == 0) sm_wred[w][16 * br + 4 * quad + i] = t;
      }
    __syncthreads();
    if (tid < 64) {
      const float mo = sm_m[tid];
      float mn = mo;
#pragma unroll
      for (int w2 = 0; w2 < 8; ++w2) mn = fmaxf(mn, sm_wred[w2][tid]);
      sm_m[tid] = mn;
      sm_alpha[tid] = __expf(mo - mn);
    }
    __syncthreads();
#pragma unroll
    for (int br = 0; br < 4; ++br)
#pragma unroll
      for (int i = 0; i < 4; ++i) {
        const int row = 16 * br + 4 * quad + i;
        const float mn = sm_m[row];
        const float p0 = __expf(acc_s[br][0][i] - mn);
        const float p1 = __expf(acc_s[br][1][i] - mn);
        acc_s[br][0][i] = p0;
        acc_s[br][1][i] = p1;
        float t = p0 + p1;
        t += __shfl_xor(t, 1);
        t += __shfl_xor(t, 2);
        t += __shfl_xor(t, 4);
        t += __shfl_xor(t, 8);
        if (lane15 == 0) sm_wsum[w][row] = t;
      }
#pragma unroll
    for (int br = 0; br < 4; ++br)
#pragma unroll
      for (int i = 0; i < 4; ++i) {
        const float al = sm_alpha[16 * br + 4 * quad + i];
#pragma unroll
        for (int bc = 0; bc < 8; ++bc) acc_o[br][bc][i] *= al;
      }
    auto writePs = [&]() {
#pragma unroll
      for (int br = 0; br < 4; ++br)
#pragma unroll
        for (int bc = 0; bc < 2; ++bc)
#pragma unroll
          for (int i = 0; i < 4; ++i) {
            const int row = 16 * br + 4 * quad + i;
            const int col = 32 * (w & 3) + 16 * bc + lane15;
            Ps[row * 128 + (((col >> 3) ^ (row & 15)) * 8) + (col & 7)] = f2bf(acc_s[br][bc][i]);
          }
    };
    if (w < 4) writePs();
    __syncthreads();
    if (tid < 64) {
      float s = 0.f;
#pragma unroll
      for (int w2 = 0; w2 < 8; ++w2) s += sm_wsum[w2][tid];
      sm_l[tid] = sm_l[tid] * sm_alpha[tid] + s;
    }
    // ---- phase C: O += P @ V, wave w owns d-cols [128w, 128w+128) ----
    auto phaseC = [&](int h) {
#pragma unroll
      for (int kst = 0; kst < 4; ++kst) {
        bf16x8 a[4];
#pragma unroll
        for (int br = 0; br < 4; ++br) {
          const int row = 16 * br + lane15;
          const int x = kst * 4 + quad;
          a[br] = *(const bf16x8*)(&Ps[row * 128 + ((x ^ (row & 15)) * 8)]);
        }
        const int ko = jb + h * 128 + kst * 32 + quad * 8;
#pragma unroll
        for (int bc = 0; bc < 8; ++bc) {
          const bf16x8 b =
              *(const bf16x8*)(Vtg + (size_t)(128 * w + 16 * bc + lane15) * 8192 + ko);
#pragma unroll
          for (int br = 0; br < 4; ++br) acc_o[br][bc] = MFMA(a[br], b, acc_o[br][bc]);
        }
      }
    };
    phaseC(0);
    __syncthreads();
    if (w >= 4) writePs();
    __syncthreads();
    phaseC(1);
  }
  __syncthreads();
  // ---- epilogue ----
  if (nsplit == 2) {
#pragma unroll
    for (int br = 0; br < 4; ++br)
#pragma unroll
      for (int bc = 0; bc < 8; ++bc)
#pragma unroll
        for (int i = 0; i < 4; ++i) {
          const int s = qrow0 + 16 * br + 4 * quad + i;
          const int col = 128 * w + 16 * bc + lane15;
          Opart[(size_t)sp * 8388608 + (size_t)s * 1024 + col] = acc_o[br][bc][i];
        }
    if (tid < 64) {
      mlb[((size_t)sp * 8192 + qrow0 + tid) * 2] = sm_m[tid];
      mlb[((size_t)sp * 8192 + qrow0 + tid) * 2 + 1] = sm_l[tid];
    }
  } else {
#pragma unroll
    for (int br = 0; br < 4; ++br)
#pragma unroll
      for (int i = 0; i < 4; ++i) {
        const int row = 16 * br + 4 * quad + i;
        const float inv = 1.0f / sm_l[row];
        const int s = qrow0 + row;
#pragma unroll
        for (int bc = 0; bc < 8; ++bc) {
          const int col = 128 * w + 16 * bc + lane15;
          ctx[(size_t)s * 1024 + col] = f2bf(acc_o[br][bc][i] * inv);
        }
      }
  }
}

// ---------------- split-K combine -> ctx bf16 ----------------
__global__ __launch_bounds__(256) void combine_kernel(
    const float* __restrict__ Opart, const float* __restrict__ mlb,
    unsigned short* __restrict__ ctx) {
  const int s = blockIdx.x;
  const int d = threadIdx.x * 4;
  const float m0 = mlb[(size_t)s * 2], l0 = mlb[(size_t)s * 2 + 1];
  const float m1 = mlb[(size_t)(8192 + s) * 2], l1 = mlb[(size_t)(8192 + s) * 2 + 1];
  const float M = fmaxf(m0, m1);
  const float a0 = __expf(m0 - M), a1 = __expf(m1 - M);
  const float inv = 1.0f / (a0 * l0 + a1 * l1);
  const f32x4 o0 = *(const f32x4*)(Opart + (size_t)s * 1024 + d);
  const f32x4 o1 = *(const f32x4*)(Opart + 8388608 + (size_t)s * 1024 + d);
  ushort4 r;
  r.x = f2bf((a0 * o0[0] + a1 * o1[0]) * inv);
  r.y = f2bf((a0 * o0[1] + a1 * o1[1]) * inv);
  r.z = f2bf((a0 * o0[2] + a1 * o1[2]) * inv);
  r.w = f2bf((a0 * o0[3] + a1 * o1[3]) * inv);
  *(ushort4*)(ctx + (size_t)s * 1024 + d) = r;
}

// ---------------- output projection: out = ctx @ w_out^T + b_out (fp32 out) ----------------
__global__ __launch_bounds__(256) void proj_kernel(
    const unsigned short* __restrict__ ctxb, const unsigned short* __restrict__ wb,
    const float* __restrict__ bias, float* __restrict__ out) {
  __shared__ unsigned short As[128 * 64], Bs[128 * 64];
  const int bx = blockIdx.x;
  const int tn = bx % 8, tm = bx / 8;
  f32x4 acc[4][4];
  gemm_tile(ctxb, wb, As, Bs, tm, tn, acc);
  const int tid = threadIdx.x, w = tid >> 6, l = tid & 63, lane15 = l & 15, quad = l >> 4;
  const int r0 = tm * 128 + 64 * (w >> 1);
  const int c0 = tn * 128 + 64 * (w & 1);
  float bo[4];
#pragma unroll
  for (int bc = 0; bc < 4; ++bc) bo[bc] = bias[c0 + 16 * bc + lane15];
#pragma unroll
  for (int br = 0; br < 4; ++br)
#pragma unroll
    for (int bc = 0; bc < 4; ++bc)
#pragma unroll
      for (int i = 0; i < 4; ++i)
        out[(size_t)(r0 + 16 * br + 4 * quad + i) * 1024 + c0 + 16 * bc + lane15] =
            acc[br][bc][i] + bo[bc];
}

extern "C" void kernel_launch(void* const* d_in, const int* in_sizes, int n_in,
                              void* d_out, int out_size, void* d_ws, size_t ws_size,
                              hipStream_t stream) {
  const float* x = (const float*)d_in[0];
  const float* wqkv = (const float*)d_in[1];
  const float* bqkv = (const float*)d_in[2];
  const float* wout = (const float*)d_in[3];
  const float* bout = (const float*)d_in[4];
  float* out = (float*)d_out;
  char* ws = (char*)d_ws;

  unsigned short* xb = (unsigned short*)(ws);                 // 16 MB
  unsigned short* wqkvb = (unsigned short*)(ws + 16777216);   // 6 MB
  unsigned short* woutb = (unsigned short*)(ws + 23068672);   // 2 MB
  unsigned short* Qp = (unsigned short*)(ws + 25165824);      // 16 MB (prescaled)
  unsigned short* Kp = (unsigned short*)(ws + 41943040);      // 16 MB
  unsigned short* Vtp = (unsigned short*)(ws + 58720256);     // 16 MB (transposed)
  unsigned short* ctx = (unsigned short*)(ws + 75497472);     // 16 MB
  float* Opart = (float*)(ws + 92274688);                     // 64 MB (split2 only)
  float* mlb = (float*)(ws + 159383552);                      // 128 KB
  const int nsplit = (ws_size >= 159514624ULL) ? 2 : 1;

  convert_kernel<<<12288, 256, 0, stream>>>(x, wqkv, wout, xb, wqkvb, woutb);
  qkv_kernel<<<1536, 256, 0, stream>>>(xb, wqkvb, bqkv, Qp, Kp, Vtp);
  flash_kernel<<<nsplit * 128, 512, 0, stream>>>(Qp, Kp, Vtp, Opart, mlb, ctx, nsplit);
  if (nsplit == 2) combine_kernel<<<8192, 256, 0, stream>>>(Opart, mlb, ctx);
  proj_kernel<<<512, 256, 0, stream>>>(ctx, woutb, bout, out);
}

// Round 2
// 1045.353 us; speedup vs baseline: 1.1551x; 1.1551x over previous
//
#include <hip/hip_runtime.h>

typedef __attribute__((ext_vector_type(4))) float f32x4;
typedef __attribute__((ext_vector_type(8))) __bf16 bf16x8;

__device__ __forceinline__ unsigned short f2bf(float f) {
  union { float f; unsigned u; } v; v.f = f;
  unsigned r = v.u + 0x7fffu + ((v.u >> 16) & 1u);
  return (unsigned short)(r >> 16);
}

__device__ __forceinline__ void gll16(const void* g, void* s) {
  __builtin_amdgcn_global_load_lds((const __attribute__((address_space(1))) unsigned int*)g,
                                   (__attribute__((address_space(3))) unsigned int*)s, 16, 0, 0);
}

#define MFMA(a, b, c) __builtin_amdgcn_mfma_f32_16x16x32_bf16((a), (b), (c), 0, 0, 0)

// ---------------- fp32 -> bf16 convert (x, w_qkv, w_out) ----------------
__global__ __launch_bounds__(256) void convert_kernel(
    const float* __restrict__ x, const float* __restrict__ wqkv, const float* __restrict__ wout,
    unsigned short* __restrict__ xb, unsigned short* __restrict__ wqkvb,
    unsigned short* __restrict__ woutb) {
  const long i4 = (long)blockIdx.x * 256 + threadIdx.x;
  const float4* src;
  unsigned short* dst;
  long j;
  if (i4 < 2097152) { src = (const float4*)x; j = i4; dst = xb; }
  else if (i4 < 2883584) { src = (const float4*)wqkv; j = i4 - 2097152; dst = wqkvb; }
  else { src = (const float4*)wout; j = i4 - 2883584; dst = woutb; }
  const float4 v = src[j];
  ushort4 r;
  r.x = f2bf(v.x); r.y = f2bf(v.y); r.z = f2bf(v.z); r.w = f2bf(v.w);
  *(ushort4*)(dst + j * 4) = r;
}

// ---------------- shared 128x128 GEMM mainloop (A, B row-major [*,1024], NT) ----------------
__device__ __forceinline__ void gemm_tile(const unsigned short* __restrict__ A,
                                          const unsigned short* __restrict__ B,
                                          unsigned short* As, unsigned short* Bs,
                                          int tm, int tn, f32x4 acc[4][4]) {
  const int tid = threadIdx.x;
  const int w = tid >> 6, l = tid & 63, lane15 = l & 15, quad = l >> 4;
#pragma unroll
  for (int br = 0; br < 4; ++br)
#pragma unroll
    for (int bc = 0; bc < 4; ++bc) acc[br][bc] = f32x4{0.f, 0.f, 0.f, 0.f};
  const int ar0 = 64 * (w >> 1), bc0 = 64 * (w & 1);
  for (int st = 0; st < 16; ++st) {
    const int kc = st * 64;
#pragma unroll
    for (int t = 0; t < 4; ++t) {
      const int ck = w * 4 + t;          // 1KB chunk id 0..15
      const int row = ck * 8 + (l >> 3); // 8 rows per chunk
      const int x = (l & 7) ^ (row & 7); // swizzled source block
      gll16(A + (size_t)(tm * 128 + row) * 1024 + kc + x * 8, As + ck * 512);
      gll16(B + (size_t)(tn * 128 + row) * 1024 + kc + x * 8, Bs + ck * 512);
    }
    __syncthreads();
#pragma unroll
    for (int kk = 0; kk < 2; ++kk) {
      bf16x8 a[4], b[4];
#pragma unroll
      for (int br = 0; br < 4; ++br) {
        const int row = ar0 + 16 * br + lane15;
        const int x = kk * 4 + quad;
        a[br] = *(const bf16x8*)(As + row * 64 + ((x ^ (row & 7)) * 8));
      }
#pragma unroll
      for (int bc = 0; bc < 4; ++bc) {
        const int row = bc0 + 16 * bc + lane15;
        const int x = kk * 4 + quad;
        b[bc] = *(const bf16x8*)(Bs + row * 64 + ((x ^ (row & 7)) * 8));
      }
#pragma unroll
      for (int br = 0; br < 4; ++br)
#pragma unroll
        for (int bc = 0; bc < 4; ++bc)
          acc[br][bc] = MFMA(a[br], b[bc], acc[br][bc]);
    }
    __syncthreads();
  }
}

// ---------------- QKV projection: qkv = x @ w_qkv^T + b; Q prescaled 1/32; V transposed ----------------
__global__ __launch_bounds__(256) void qkv_kernel(
    const unsigned short* __restrict__ xb, const unsigned short* __restrict__ wb,
    const float* __restrict__ bias, unsigned short* __restrict__ Qp,
    unsigned short* __restrict__ Kp, unsigned short* __restrict__ Vtp) {
  __shared__ unsigned short As[128 * 64], Bs[128 * 64];
  const int bx = blockIdx.x;
  const int tn = bx % 24, tm = bx / 24;
  f32x4 acc[4][4];
  gemm_tile(xb, wb, As, Bs, tm, tn, acc);
  const int tid = threadIdx.x, w = tid >> 6, l = tid & 63, lane15 = l & 15, quad = l >> 4;
  const int r0 = tm * 128 + 64 * (w >> 1);
  const int c0 = tn * 128 + 64 * (w & 1);
  float bq[4];
#pragma unroll
  for (int bc = 0; bc < 4; ++bc) bq[bc] = bias[c0 + 16 * bc + lane15];
  if (tn < 8) {  // Q region, fold 1/sqrt(D)
#pragma unroll
    for (int br = 0; br < 4; ++br)
#pragma unroll
      for (int bc = 0; bc < 4; ++bc)
#pragma unroll
        for (int i = 0; i < 4; ++i)
          Qp[(size_t)(r0 + 16 * br + 4 * quad + i) * 1024 + c0 + 16 * bc + lane15] =
              f2bf((acc[br][bc][i] + bq[bc]) * 0.03125f);
  } else if (tn < 16) {  // K region
#pragma unroll
    for (int br = 0; br < 4; ++br)
#pragma unroll
      for (int bc = 0; bc < 4; ++bc)
#pragma unroll
        for (int i = 0; i < 4; ++i)
          Kp[(size_t)(r0 + 16 * br + 4 * quad + i) * 1024 + c0 - 1024 + 16 * bc + lane15] =
              f2bf(acc[br][bc][i] + bq[bc]);
  } else {  // V region -> transposed store Vt[d][s]
#pragma unroll
    for (int br = 0; br < 4; ++br)
#pragma unroll
      for (int bc = 0; bc < 4; ++bc) {
        ushort4 pk;
        pk.x = f2bf(acc[br][bc][0] + bq[bc]);
        pk.y = f2bf(acc[br][bc][1] + bq[bc]);
        pk.z = f2bf(acc[br][bc][2] + bq[bc]);
        pk.w = f2bf(acc[br][bc][3] + bq[bc]);
        *(ushort4*)(Vtp + (size_t)(c0 - 2048 + 16 * bc + lane15) * 8192 + r0 + 16 * br + 4 * quad) = pk;
      }
  }
}

// ---------------- flash attention v2: 1024 threads (16 waves), BM=64, BN=256 ----------------
// Q tile resident in LDS (128 KB, loaded once). Phase A barrier-free: wave w owns S-cols
// [16w,16w+16), K fragments direct global->VGPR. Phase C: wave w owns d-cols [64w,64w+64).
// acc_o[4][4]=64 + acc_s[4]=16 regs -> 4 waves/SIMD (16 waves/CU resident). 5 barriers/j.
__global__ __launch_bounds__(1024, 4) void flash_kernel(
    const unsigned short* __restrict__ Qg, const unsigned short* __restrict__ Kg,
    const unsigned short* __restrict__ Vtg, float* __restrict__ Opart,
    float* __restrict__ mlb, unsigned short* __restrict__ ctx, int nsplit) {
  __shared__ unsigned short Qs[64 * 1024];  // 128 KB, XOR-swizzled (16B blocks, mask row&15)
  __shared__ unsigned short Ps[64 * 128];   // 16 KB, one 128-col half of P at a time
  __shared__ float wred[64 * 16];           // [row][wave] partial col-max
  __shared__ float wsum[64 * 16];           // [row][wave] partial row-sum
  __shared__ float sm_m[64], sm_alpha[64], sm_l[64];

  const int tid = threadIdx.x;
  const int w = tid >> 6, l = tid & 63, lane15 = l & 15, quad = l >> 4;
  const int bx = blockIdx.x;
  const int qt = (nsplit == 2) ? (bx >> 1) : bx;
  const int sp = (nsplit == 2) ? (bx & 1) : 0;
  const int jper = (nsplit == 2) ? 16 : 32;
  const int jstart = sp * jper;
  const int qrow0 = qt * 64;

  // ---- stage Q once: 8x gll16 per thread (1KB chunk per (wave,t)) ----
#pragma unroll
  for (int t = 0; t < 8; ++t) {
    const int ck = w * 8 + t;          // 0..127 half-row chunks
    const int r = ck >> 1;             // row 0..63
    const int xp = (ck & 1) * 64 + l;  // swizzled block 0..127
    const int x = (xp & 112) | ((xp & 15) ^ (r & 15));
    gll16(Qg + (size_t)(qrow0 + r) * 1024 + x * 8, Qs + ck * 512);
  }
  if (tid < 64) { sm_m[tid] = -1e30f; sm_l[tid] = 0.f; }

  f32x4 acc_o[4][4];
#pragma unroll
  for (int br = 0; br < 4; ++br)
#pragma unroll
    for (int bc = 0; bc < 4; ++bc) acc_o[br][bc] = f32x4{0.f, 0.f, 0.f, 0.f};

  __syncthreads();

  for (int j = jstart; j < jstart + jper; ++j) {
    const int jb = j * 256;
    // ---- phase A (no barriers): S cols [16w,16w+16), K direct from global ----
    f32x4 acc_s[4];
#pragma unroll
    for (int br = 0; br < 4; ++br) acc_s[br] = f32x4{0.f, 0.f, 0.f, 0.f};
    const unsigned short* kp = Kg + (size_t)(jb + 16 * w + lane15) * 1024 + quad * 8;
#pragma unroll 4
    for (int kst = 0; kst < 32; ++kst) {
      const bf16x8 b = *(const bf16x8*)(kp + kst * 32);
#pragma unroll
      for (int br = 0; br < 4; ++br) {
        const int row = 16 * br + lane15;
        const int xq = kst * 4 + quad;
        const int xp = (xq & 112) | ((xq & 15) ^ (row & 15));
        const bf16x8 a = *(const bf16x8*)(Qs + row * 1024 + xp * 8);
        acc_s[br] = MFMA(a, b, acc_s[br]);
      }
    }
    // ---- wave-local col-max (16 cols) -> wred ----
#pragma unroll
    for (int br = 0; br < 4; ++br)
#pragma unroll
      for (int i = 0; i < 4; ++i) {
        float t = acc_s[br][i];
        t = fmaxf(t, __shfl_xor(t, 1));
        t = fmaxf(t, __shfl_xor(t, 2));
        t = fmaxf(t, __shfl_xor(t, 4));
        t = fmaxf(t, __shfl_xor(t, 8));
        if (lane15 == 0) wred[(16 * br + 4 * quad + i) * 16 + w] = t;
      }
    __syncthreads();  // B1
    if (tid < 64) {
      const f32x4 r0 = *(const f32x4*)&wred[tid * 16 + 0];
      const f32x4 r1 = *(const f32x4*)&wred[tid * 16 + 4];
      const f32x4 r2 = *(const f32x4*)&wred[tid * 16 + 8];
      const f32x4 r3 = *(const f32x4*)&wred[tid * 16 + 12];
      float mn = fmaxf(fmaxf(fmaxf(r0[0], r0[1]), fmaxf(r0[2], r0[3])),
                       fmaxf(fmaxf(r1[0], r1[1]), fmaxf(r1[2], r1[3])));
      mn = fmaxf(mn, fmaxf(fmaxf(fmaxf(r2[0], r2[1]), fmaxf(r2[2], r2[3])),
                           fmaxf(fmaxf(r3[0], r3[1]), fmaxf(r3[2], r3[3]))));
      const float mo = sm_m[tid];
      const float m2 = fmaxf(mo, mn);
      sm_m[tid] = m2;
      sm_alpha[tid] = __expf(mo - m2);
    }
    __syncthreads();  // B2
    // ---- p = exp(s-m), O *= alpha, row-sums, stash P half0 ----
#pragma unroll
    for (int br = 0; br < 4; ++br) {
      const f32x4 mv = *(const f32x4*)&sm_m[16 * br + 4 * quad];
      const f32x4 av = *(const f32x4*)&sm_alpha[16 * br + 4 * quad];
#pragma unroll
      for (int i = 0; i < 4; ++i) {
        const float p = __expf(acc_s[br][i] - mv[i]);
        acc_s[br][i] = p;
        float t = p;
        t += __shfl_xor(t, 1);
        t += __shfl_xor(t, 2);
        t += __shfl_xor(t, 4);
        t += __shfl_xor(t, 8);
        if (lane15 == 0) wsum[(16 * br + 4 * quad + i) * 16 + w] = t;
      }
#pragma unroll
      for (int bc = 0; bc < 4; ++bc) {
#pragma unroll
        for (int i = 0; i < 4; ++i) acc_o[br][bc][i] *= av[i];
      }
    }
    auto writeP = [&]() {
      const int col = ((w & 7) << 4) + lane15;  // 0..127 within half
      const int xb2 = col >> 3, cl = col & 7;
#pragma unroll
      for (int br = 0; br < 4; ++br)
#pragma unroll
        for (int i = 0; i < 4; ++i) {
          const int row = 16 * br + 4 * quad + i;
          Ps[row * 128 + ((xb2 ^ (row & 15)) << 3) + cl] = f2bf(acc_s[br][i]);
        }
    };
    if (w < 8) writeP();
    __syncthreads();  // B3
    if (tid < 64) {  // l update (overlaps phase C of other waves)
      const f32x4 s0 = *(const f32x4*)&wsum[tid * 16 + 0];
      const f32x4 s1 = *(const f32x4*)&wsum[tid * 16 + 4];
      const f32x4 s2 = *(const f32x4*)&wsum[tid * 16 + 8];
      const f32x4 s3 = *(const f32x4*)&wsum[tid * 16 + 12];
      const float s = (s0[0] + s0[1] + s0[2] + s0[3]) + (s1[0] + s1[1] + s1[2] + s1[3]) +
                      (s2[0] + s2[1] + s2[2] + s2[3]) + (s3[0] + s3[1] + s3[2] + s3[3]);
      sm_l[tid] = sm_l[tid] * sm_alpha[tid] + s;
    }
    // ---- phase C: O += P @ V, d-cols [64w,64w+64), V direct from global ----
    auto phaseC = [&](int h) {
      const unsigned short* vp =
          Vtg + (size_t)(64 * w + lane15) * 8192 + jb + 128 * h + quad * 8;
#pragma unroll
      for (int kk = 0; kk < 4; ++kk) {
        bf16x8 a[4];
#pragma unroll
        for (int br = 0; br < 4; ++br) {
          const int row = 16 * br + lane15;
          const int x = kk * 4 + quad;
          a[br] = *(const bf16x8*)(Ps + row * 128 + ((x ^ (row & 15)) << 3));
        }
#pragma unroll
        for (int bc = 0; bc < 4; ++bc) {
          const bf16x8 b = *(const bf16x8*)(vp + (size_t)(16 * bc) * 8192 + kk * 32);
#pragma unroll
          for (int br = 0; br < 4; ++br) acc_o[br][bc] = MFMA(a[br], b, acc_o[br][bc]);
        }
      }
    };
    phaseC(0);
    __syncthreads();  // B4
    if (w >= 8) writeP();
    __syncthreads();  // B5
    phaseC(1);
  }
  __syncthreads();
  // ---- epilogue ----
  if (nsplit == 2) {
#pragma unroll
    for (int br = 0; br < 4; ++br)
#pragma unroll
      for (int bc = 0; bc < 4; ++bc)
#pragma unroll
        for (int i = 0; i < 4; ++i) {
          const int s = qrow0 + 16 * br + 4 * quad + i;
          const int col = 64 * w + 16 * bc + lane15;
          Opart[(size_t)sp * 8388608 + (size_t)s * 1024 + col] = acc_o[br][bc][i];
        }
    if (tid < 64) {
      mlb[((size_t)sp * 8192 + qrow0 + tid) * 2] = sm_m[tid];
      mlb[((size_t)sp * 8192 + qrow0 + tid) * 2 + 1] = sm_l[tid];
    }
  } else {
#pragma unroll
    for (int br = 0; br < 4; ++br) {
      const f32x4 lv = *(const f32x4*)&sm_l[16 * br + 4 * quad];
#pragma unroll
      for (int i = 0; i < 4; ++i) {
        const float inv = 1.0f / lv[i];
        const int s = qrow0 + 16 * br + 4 * quad + i;
#pragma unroll
        for (int bc = 0; bc < 4; ++bc)
          ctx[(size_t)s * 1024 + 64 * w + 16 * bc + lane15] = f2bf(acc_o[br][bc][i] * inv);
      }
    }
  }
}

// ---------------- split-K combine -> ctx bf16 ----------------
__global__ __launch_bounds__(256) void combine_kernel(
    const float* __restrict__ Opart, const float* __restrict__ mlb,
    unsigned short* __restrict__ ctx) {
  const int s = blockIdx.x;
  const int d = threadIdx.x * 4;
  const float m0 = mlb[(size_t)s * 2], l0 = mlb[(size_t)s * 2 + 1];
  const float m1 = mlb[(size_t)(8192 + s) * 2], l1 = mlb[(size_t)(8192 + s) * 2 + 1];
  const float M = fmaxf(m0, m1);
  const float a0 = __expf(m0 - M), a1 = __expf(m1 - M);
  const float inv = 1.0f / (a0 * l0 + a1 * l1);
  const f32x4 o0 = *(const f32x4*)(Opart + (size_t)s * 1024 + d);
  const f32x4 o1 = *(const f32x4*)(Opart + 8388608 + (size_t)s * 1024 + d);
  ushort4 r;
  r.x = f2bf((a0 * o0[0] + a1 * o1[0]) * inv);
  r.y = f2bf((a0 * o0[1] + a1 * o1[1]) * inv);
  r.z = f2bf((a0 * o0[2] + a1 * o1[2]) * inv);
  r.w = f2bf((a0 * o0[3] + a1 * o1[3]) * inv);
  *(ushort4*)(ctx + (size_t)s * 1024 + d) = r;
}

// ---------------- output projection: out = ctx @ w_out^T + b_out (fp32 out) ----------------
__global__ __launch_bounds__(256) void proj_kernel(
    const unsigned short* __restrict__ ctxb, const unsigned short* __restrict__ wb,
    const float* __restrict__ bias, float* __restrict__ out) {
  __shared__ unsigned short As[128 * 64], Bs[128 * 64];
  const int bx = blockIdx.x;
  const int tn = bx % 8, tm = bx / 8;
  f32x4 acc[4][4];
  gemm_tile(ctxb, wb, As, Bs, tm, tn, acc);
  const int tid = threadIdx.x, w = tid >> 6, l = tid & 63, lane15 = l & 15, quad = l >> 4;
  const int r0 = tm * 128 + 64 * (w >> 1);
  const int c0 = tn * 128 + 64 * (w & 1);
  float bo[4];
#pragma unroll
  for (int bc = 0; bc < 4; ++bc) bo[bc] = bias[c0 + 16 * bc + lane15];
#pragma unroll
  for (int br = 0; br < 4; ++br)
#pragma unroll
    for (int bc = 0; bc < 4; ++bc)
#pragma unroll
      for (int i = 0; i < 4; ++i)
        out[(size_t)(r0 + 16 * br + 4 * quad + i) * 1024 + c0 + 16 * bc + lane15] =
            acc[br][bc][i] + bo[bc];
}

extern "C" void kernel_launch(void* const* d_in, const int* in_sizes, int n_in,
                              void* d_out, int out_size, void* d_ws, size_t ws_size,
                              hipStream_t stream) {
  const float* x = (const float*)d_in[0];
  const float* wqkv = (const float*)d_in[1];
  const float* bqkv = (const float*)d_in[2];
  const float* wout = (const float*)d_in[3];
  const float* bout = (const float*)d_in[4];
  float* out = (float*)d_out;
  char* ws = (char*)d_ws;

  unsigned short* xb = (unsigned short*)(ws);                 // 16 MB
  unsigned short* wqkvb = (unsigned short*)(ws + 16777216);   // 6 MB
  unsigned short* woutb = (unsigned short*)(ws + 23068672);   // 2 MB
  unsigned short* Qp = (unsigned short*)(ws + 25165824);      // 16 MB (prescaled)
  unsigned short* Kp = (unsigned short*)(ws + 41943040);      // 16 MB
  unsigned short* Vtp = (unsigned short*)(ws + 58720256);     // 16 MB (transposed)
  unsigned short* ctx = (unsigned short*)(ws + 75497472);     // 16 MB
  float* Opart = (float*)(ws + 92274688);                     // 64 MB (split2 only)
  float* mlb = (float*)(ws + 159383552);                      // 128 KB
  const int nsplit = (ws_size >= 159514624ULL) ? 2 : 1;

  convert_kernel<<<12288, 256, 0, stream>>>(x, wqkv, wout, xb, wqkvb, woutb);
  qkv_kernel<<<1536, 256, 0, stream>>>(xb, wqkvb, bqkv, Qp, Kp, Vtp);
  flash_kernel<<<nsplit * 128, 1024, 0, stream>>>(Qp, Kp, Vtp, Opart, mlb, ctx, nsplit);
  if (nsplit == 2) combine_kernel<<<8192, 256, 0, stream>>>(Opart, mlb, ctx);
  proj_kernel<<<512, 256, 0, stream>>>(ctx, woutb, bout, out);
}